// Round 5
// baseline (450.088 us; speedup 1.0000x reference)
//
#include <hip/hip_runtime.h>
#include <hip/hip_fp16.h>

#define NN 50000
#define BN_EPS 1e-5f

typedef unsigned int uint;
typedef unsigned short ushort;

__device__ __forceinline__ ushort f2h(float x) {
    return __half_as_ushort(__float2half_rn(x));
}
__device__ __forceinline__ float h_lo(uint u) {
    return __half2float(__ushort_as_half((ushort)(u & 0xFFFFu)));
}
__device__ __forceinline__ float h_hi(uint u) {
    return __half2float(__ushort_as_half((ushort)(u >> 16)));
}
__device__ __forceinline__ void unpack8(uint4 v, float* f) {
    f[0] = h_lo(v.x); f[1] = h_hi(v.x);
    f[2] = h_lo(v.y); f[3] = h_hi(v.y);
    f[4] = h_lo(v.z); f[5] = h_hi(v.z);
    f[6] = h_lo(v.w); f[7] = h_hi(v.w);
}

// ================= CSR build (by dst) =================
__global__ __launch_bounds__(256) void hist_kernel(
    const int* __restrict__ ei, int* __restrict__ deg, int E)
{
    int e = blockIdx.x * 256 + threadIdx.x;
    if (e < E) atomicAdd(&deg[ei[E + e]], 1);
}

__global__ __launch_bounds__(256) void bsum_kernel(
    const int* __restrict__ deg, int* __restrict__ bsum)
{
    int i = blockIdx.x * 256 + threadIdx.x;
    int v = (i < NN) ? deg[i] : 0;
    #pragma unroll
    for (int off = 32; off >= 1; off >>= 1) v += __shfl_down(v, off, 64);
    __shared__ int ws[4];
    int lane = threadIdx.x & 63, wid = threadIdx.x >> 6;
    if (lane == 0) ws[wid] = v;
    __syncthreads();
    if (threadIdx.x == 0) bsum[blockIdx.x] = ws[0] + ws[1] + ws[2] + ws[3];
}

__global__ __launch_bounds__(256) void bscan_kernel(
    int* __restrict__ bsum, int* __restrict__ rowPtr, int NB, int E)
{
    int lane = threadIdx.x & 63, wid = threadIdx.x >> 6;
    int v = (threadIdx.x < NB) ? bsum[threadIdx.x] : 0;
    int incl = v;
    #pragma unroll
    for (int off = 1; off < 64; off <<= 1) {
        int t = __shfl_up(incl, off, 64);
        if (lane >= off) incl += t;
    }
    __shared__ int ws[4];
    if (lane == 63) ws[wid] = incl;
    __syncthreads();
    int woff = 0;
    if (wid > 0) woff += ws[0];
    if (wid > 1) woff += ws[1];
    if (wid > 2) woff += ws[2];
    if (threadIdx.x < NB) bsum[threadIdx.x] = incl - v + woff;
    if (threadIdx.x == 0) rowPtr[NN] = E;
}

__global__ __launch_bounds__(256) void scan_apply_kernel(
    const int* __restrict__ deg, const int* __restrict__ bsum,
    int* __restrict__ rowPtr, int* __restrict__ cursor)
{
    int i = blockIdx.x * 256 + threadIdx.x;
    int lane = threadIdx.x & 63, wid = threadIdx.x >> 6;
    int v = (i < NN) ? deg[i] : 0;
    int incl = v;
    #pragma unroll
    for (int off = 1; off < 64; off <<= 1) {
        int t = __shfl_up(incl, off, 64);
        if (lane >= off) incl += t;
    }
    __shared__ int ws[4];
    if (lane == 63) ws[wid] = incl;
    __syncthreads();
    int woff = bsum[blockIdx.x];
    if (wid > 0) woff += ws[0];
    if (wid > 1) woff += ws[1];
    if (wid > 2) woff += ws[2];
    int excl = incl - v + woff;
    if (i < NN) { rowPtr[i] = excl; cursor[i] = excl; }
}

__global__ __launch_bounds__(256) void fill_csr_kernel(
    const int* __restrict__ ei, int* __restrict__ cursor,
    int* __restrict__ csr_src, int E)
{
    int e = blockIdx.x * 256 + threadIdx.x;
    if (e < E) {
        int pos = atomicAdd(&cursor[ei[E + e]], 1);
        csr_src[pos] = ei[e];
    }
}

// ================= fp32 -> fp16 table conversion (x) =================
__global__ __launch_bounds__(256) void cvt_f16_kernel(
    const float* __restrict__ in, ushort* __restrict__ out, int n8)
{
    int i = blockIdx.x * 256 + threadIdx.x;
    if (i >= n8) return;
    const float4* in4 = (const float4*)in;
    float4 a = in4[2 * i], b = in4[2 * i + 1];
    uint4 o;
    o.x = (uint)f2h(a.x) | ((uint)f2h(a.y) << 16);
    o.y = (uint)f2h(a.z) | ((uint)f2h(a.w) << 16);
    o.z = (uint)f2h(b.x) | ((uint)f2h(b.y) << 16);
    o.w = (uint)f2h(b.z) | ((uint)f2h(b.w) << 16);
    ((uint4*)out)[i] = o;
}

// ===== fused: [BN+ReLU prev] + CSR-gather(fp16) + (1+eps)*self -> fp32 MLP + BN stats =====
// 512 threads = 8 waves; wave owns one row (wave-private s_h[w], no barriers in main loop).
// Gather: 16B/lane = 8 fp16 cols; EPW edges per wave issue; csr index prefetched 1 iter ahead.
template<int F, bool APPLY>
__global__ __launch_bounds__(512, 6) void gin_mlp_kernel(
    const ushort* __restrict__ xin,
    const float* __restrict__ stats_in, const float* __restrict__ g_in,
    const float* __restrict__ be_in,
    const int* __restrict__ rowPtr, const int* __restrict__ csr_src,
    const float* __restrict__ eps_p,
    const float* __restrict__ wa, const float* __restrict__ ba,
    const float* __restrict__ wb, const float* __restrict__ bb,
    ushort* __restrict__ h_out, float* __restrict__ stats_out)
{
    constexpr int C8  = F / 8;     // uint4 chunks per row (16 or 8)
    constexpr int EPW = 64 / C8;   // edges per wave issue (4 or 8)

    __shared__ float s_wa[F * 64];
    __shared__ float s_wb[64 * 64];
    __shared__ float s_h[8][F];

    for (int i = threadIdx.x; i < F * 64; i += 512) s_wa[i] = wa[i];
    for (int i = threadIdx.x; i < 64 * 64; i += 512) s_wb[i] = wb[i];

    const int w    = threadIdx.x >> 6;
    const int lane = threadIdx.x & 63;
    const int cc   = lane % C8;    // chunk within row
    const int gph  = lane / C8;    // edge slot
    const float eps1 = 1.0f + eps_p[0];
    const float ba_c = ba[lane];
    const float bb_c = bb[lane];

    // BN affine of PREVIOUS layer for this lane's 8 gather columns
    float scv[8], shv[8];
    if (APPLY) {
        int c0 = 8 * cc;
        #pragma unroll
        for (int j = 0; j < 8; j++) {
            float mean = stats_in[c0 + j] * (1.0f / NN);
            float var  = stats_in[64 + c0 + j] * (1.0f / NN) - mean * mean;
            float rstd = rsqrtf(var + BN_EPS);
            float s    = rstd * g_in[c0 + j];
            scv[j] = s;
            shv[j] = be_in[c0 + j] - mean * s;
        }
    }
    __syncthreads();  // weights staged

    float sum = 0.0f, sumsq = 0.0f;
    const uint4* x4 = (const uint4*)xin;
    const int stride = gridDim.x * 8;

    for (int row = blockIdx.x * 8 + w; row < NN; row += stride) {
        int beg = rowPtr[row], end = rowPtr[row + 1];
        float a[8];
        #pragma unroll
        for (int j = 0; j < 8; j++) a[j] = 0.0f;

        if (gph == 0) {   // self term
            uint4 v = x4[(size_t)row * C8 + cc];
            float f[8]; unpack8(v, f);
            #pragma unroll
            for (int j = 0; j < 8; j++) {
                if (APPLY) f[j] = fmaxf(fmaf(f[j], scv[j], shv[j]), 0.0f);
                a[j] = eps1 * f[j];
            }
        }
        // edge loop, csr index prefetched one iteration ahead
        int e  = beg + gph;
        int sn = (e < end) ? csr_src[e] : -1;
        while (sn >= 0) {
            int sc = sn;
            e += EPW;
            sn = (e < end) ? csr_src[e] : -1;
            uint4 v = x4[(size_t)sc * C8 + cc];
            float f[8]; unpack8(v, f);
            #pragma unroll
            for (int j = 0; j < 8; j++) {
                if (APPLY) f[j] = fmaxf(fmaf(f[j], scv[j], shv[j]), 0.0f);
                a[j] += f[j];
            }
        }
        // reduce across edge slots
        #pragma unroll
        for (int off = C8; off < 64; off <<= 1) {
            #pragma unroll
            for (int j = 0; j < 8; j++) a[j] += __shfl_xor(a[j], off, 64);
        }
        if (gph == 0) {
            float4 p0 = {a[0], a[1], a[2], a[3]};
            float4 p1 = {a[4], a[5], a[6], a[7]};
            ((float4*)(&s_h[w][8 * cc]))[0] = p0;
            ((float4*)(&s_h[w][8 * cc]))[1] = p1;
        }
        // GEMM1 + ReLU (wave-private LDS => no barrier)
        float acc = ba_c;
        #pragma unroll 8
        for (int k = 0; k < F; k++)
            acc = fmaf(s_h[w][k], s_wa[k * 64 + lane], acc);
        float t = fmaxf(acc, 0.0f);
        s_h[w][lane] = t;
        // GEMM2 + ReLU
        float acc2 = bb_c;
        #pragma unroll 8
        for (int k = 0; k < 64; k++)
            acc2 = fmaf(s_h[w][k], s_wb[k * 64 + lane], acc2);
        float h = fmaxf(acc2, 0.0f);
        sum += h;
        sumsq += h * h;
        // pack pairs of lanes -> one uint store per even lane (fp16 h table)
        ushort hb = f2h(h);
        int oth = __shfl_xor((int)hb, 1, 64);
        if ((lane & 1) == 0)
            ((uint*)h_out)[(size_t)row * 32 + (lane >> 1)] = (uint)hb | ((uint)oth << 16);
    }

    // block BN-stat reduction
    __syncthreads();
    s_h[w][lane] = sum;
    __syncthreads();
    if (w == 0) {
        float s = 0;
        #pragma unroll
        for (int j = 0; j < 8; j++) s += s_h[j][lane];
        atomicAdd(&stats_out[lane], s);
    }
    __syncthreads();
    s_h[w][lane] = sumsq;
    __syncthreads();
    if (w == 0) {
        float s = 0;
        #pragma unroll
        for (int j = 0; j < 8; j++) s += s_h[j][lane];
        atomicAdd(&stats_out[64 + lane], s);
    }
}

// ---------------- final: BN+ReLU of layer 3 (fp16 h), then (N,64)@(64,10)+b ----------------
__global__ __launch_bounds__(256) void final_linear_kernel(
    const ushort* __restrict__ h, const float* __restrict__ stats,
    const float* __restrict__ g, const float* __restrict__ be,
    const float* __restrict__ w, const float* __restrict__ b,
    float* __restrict__ out)
{
    __shared__ float s_w[640];
    __shared__ float s_b[10];
    __shared__ float s_scale[64];
    __shared__ float s_shift[64];
    for (int i = threadIdx.x; i < 640; i += 256) s_w[i] = w[i];
    if (threadIdx.x < 10) s_b[threadIdx.x] = b[threadIdx.x];
    if (threadIdx.x < 64) {
        int c = threadIdx.x;
        float mean = stats[c] * (1.0f / NN);
        float var  = stats[64 + c] * (1.0f / NN) - mean * mean;
        float rstd = rsqrtf(var + BN_EPS);
        float s    = rstd * g[c];
        s_scale[c] = s;
        s_shift[c] = be[c] - mean * s;
    }
    __syncthreads();
    int row = blockIdx.x * 256 + threadIdx.x;
    if (row >= NN) return;
    float acc[10];
    #pragma unroll
    for (int c = 0; c < 10; c++) acc[c] = s_b[c];
    const uint4* hr = (const uint4*)(h + (size_t)row * 64);
    #pragma unroll
    for (int ch = 0; ch < 8; ch++) {
        uint4 v = hr[ch];
        float f[8]; unpack8(v, f);
        #pragma unroll
        for (int j = 0; j < 8; j++) {
            int k = ch * 8 + j;
            float val = fmaxf(fmaf(f[j], s_scale[k], s_shift[k]), 0.0f);
            #pragma unroll
            for (int c = 0; c < 10; c++) acc[c] = fmaf(val, s_w[k * 10 + c], acc[c]);
        }
    }
    #pragma unroll
    for (int c = 0; c < 10; c++) out[row * 10 + c] = acc[c];
}

extern "C" void kernel_launch(void* const* d_in, const int* in_sizes, int n_in,
                              void* d_out, int out_size, void* d_ws, size_t ws_size,
                              hipStream_t stream)
{
    const float* x  = (const float*)d_in[0];
    const int*   ei = (const int*)d_in[1];
    const int E = in_sizes[1] / 2;

    const float* eps[3]; const float* wa[3]; const float* ba[3];
    const float* wb[3];  const float* bb[3]; const float* g[3]; const float* be[3];
    for (int i = 0; i < 3; i++) {
        int base = 2 + 7 * i;
        eps[i] = (const float*)d_in[base + 0];
        wa[i]  = (const float*)d_in[base + 1];
        ba[i]  = (const float*)d_in[base + 2];
        wb[i]  = (const float*)d_in[base + 3];
        bb[i]  = (const float*)d_in[base + 4];
        g[i]   = (const float*)d_in[base + 5];
        be[i]  = (const float*)d_in[base + 6];
    }
    const float* lin_w = (const float*)d_in[23];
    const float* lin_b = (const float*)d_in[24];
    float* out = (float*)d_out;

    // workspace layout
    const int NB = (NN + 255) / 256;
    char*  base   = (char*)d_ws;
    int*   deg    = (int*)base;               // NN
    int*   rowPtr = deg + NN;                 // NN+1
    int*   cursor = rowPtr + NN + 1;          // NN
    int*   bsum   = cursor + NN;              // 256
    int*   csrsrc = bsum + 256;               // E
    size_t ioff   = (char*)(csrsrc + E) - base;
    ushort* xhf   = (ushort*)(base + ((ioff + 15) & ~(size_t)15));  // NN*128
    ushort* hA    = xhf + (size_t)NN * 128;   // NN*64
    ushort* hB    = hA + (size_t)NN * 64;     // NN*64
    float* stats  = (float*)(hB + (size_t)NN * 64);  // 3*128

    // ---- CSR build + x conversion ----
    hipMemsetAsync(deg, 0, NN * sizeof(int), stream);
    hipMemsetAsync(stats, 0, 3 * 128 * sizeof(float), stream);
    hist_kernel<<<(E + 255) / 256, 256, 0, stream>>>(ei, deg, E);
    cvt_f16_kernel<<<(NN * 128 / 8 + 255) / 256, 256, 0, stream>>>(x, xhf, NN * 128 / 8);
    bsum_kernel<<<NB, 256, 0, stream>>>(deg, bsum);
    bscan_kernel<<<1, 256, 0, stream>>>(bsum, rowPtr, NB, E);
    scan_apply_kernel<<<NB, 256, 0, stream>>>(deg, bsum, rowPtr, cursor);
    fill_csr_kernel<<<(E + 255) / 256, 256, 0, stream>>>(ei, cursor, csrsrc, E);

    // ---- layer 1 (F=128) ----
    gin_mlp_kernel<128, false><<<768, 512, 0, stream>>>(
        xhf, nullptr, nullptr, nullptr, rowPtr, csrsrc, eps[0],
        wa[0], ba[0], wb[0], bb[0], hA, stats);
    // ---- layer 2 (F=64, BN1+ReLU fused into gather) ----
    gin_mlp_kernel<64, true><<<1024, 512, 0, stream>>>(
        hA, stats, g[0], be[0], rowPtr, csrsrc, eps[1],
        wa[1], ba[1], wb[1], bb[1], hB, stats + 128);
    // ---- layer 3 (F=64, BN2+ReLU fused) ----
    gin_mlp_kernel<64, true><<<1024, 512, 0, stream>>>(
        hB, stats + 128, g[1], be[1], rowPtr, csrsrc, eps[2],
        wa[2], ba[2], wb[2], bb[2], hA, stats + 256);
    // ---- final linear with BN3+ReLU fused ----
    final_linear_kernel<<<(NN + 255) / 256, 256, 0, stream>>>(
        hA, stats + 256, g[2], be[2], lin_w, lin_b, out);
}

// Round 6
// 404.734 us; speedup vs baseline: 1.1121x; 1.1121x over previous
//
#include <hip/hip_runtime.h>
#include <hip/hip_fp16.h>

#define NN 50000
#define NGROUP 3125   // NN / 16 (exact)
#define BN_EPS 1e-5f

typedef unsigned int uint;
typedef unsigned short ushort;
typedef _Float16 half8 __attribute__((ext_vector_type(8)));
typedef float floatx4 __attribute__((ext_vector_type(4)));

__device__ __forceinline__ int aswz(int slot) { return slot ^ ((slot >> 4) & 7); }

__device__ __forceinline__ float h_lo(uint u) {
    return __half2float(__ushort_as_half((ushort)(u & 0xFFFFu)));
}
__device__ __forceinline__ float h_hi(uint u) {
    return __half2float(__ushort_as_half((ushort)(u >> 16)));
}
__device__ __forceinline__ void unpack8(uint4 v, float* f) {
    f[0] = h_lo(v.x); f[1] = h_hi(v.x);
    f[2] = h_lo(v.y); f[3] = h_hi(v.y);
    f[4] = h_lo(v.z); f[5] = h_hi(v.z);
    f[6] = h_lo(v.w); f[7] = h_hi(v.w);
}
__device__ __forceinline__ ushort f2h(float x) {
    return __half_as_ushort(__float2half_rn(x));
}

// ================= CSR build (by dst) =================
__global__ __launch_bounds__(256) void hist_kernel(
    const int* __restrict__ ei, int* __restrict__ deg, int E)
{
    int e = blockIdx.x * 256 + threadIdx.x;
    if (e < E) atomicAdd(&deg[ei[E + e]], 1);
}

__global__ __launch_bounds__(256) void bsum_kernel(
    const int* __restrict__ deg, int* __restrict__ bsum)
{
    int i = blockIdx.x * 256 + threadIdx.x;
    int v = (i < NN) ? deg[i] : 0;
    #pragma unroll
    for (int off = 32; off >= 1; off >>= 1) v += __shfl_down(v, off, 64);
    __shared__ int ws[4];
    int lane = threadIdx.x & 63, wid = threadIdx.x >> 6;
    if (lane == 0) ws[wid] = v;
    __syncthreads();
    if (threadIdx.x == 0) bsum[blockIdx.x] = ws[0] + ws[1] + ws[2] + ws[3];
}

__global__ __launch_bounds__(256) void bscan_kernel(
    int* __restrict__ bsum, int* __restrict__ rowPtr, int NB, int E)
{
    int lane = threadIdx.x & 63, wid = threadIdx.x >> 6;
    int v = (threadIdx.x < NB) ? bsum[threadIdx.x] : 0;
    int incl = v;
    #pragma unroll
    for (int off = 1; off < 64; off <<= 1) {
        int t = __shfl_up(incl, off, 64);
        if (lane >= off) incl += t;
    }
    __shared__ int ws[4];
    if (lane == 63) ws[wid] = incl;
    __syncthreads();
    int woff = 0;
    if (wid > 0) woff += ws[0];
    if (wid > 1) woff += ws[1];
    if (wid > 2) woff += ws[2];
    if (threadIdx.x < NB) bsum[threadIdx.x] = incl - v + woff;
    if (threadIdx.x == 0) rowPtr[NN] = E;
}

__global__ __launch_bounds__(256) void scan_apply_kernel(
    const int* __restrict__ deg, const int* __restrict__ bsum,
    int* __restrict__ rowPtr, int* __restrict__ cursor)
{
    int i = blockIdx.x * 256 + threadIdx.x;
    int lane = threadIdx.x & 63, wid = threadIdx.x >> 6;
    int v = (i < NN) ? deg[i] : 0;
    int incl = v;
    #pragma unroll
    for (int off = 1; off < 64; off <<= 1) {
        int t = __shfl_up(incl, off, 64);
        if (lane >= off) incl += t;
    }
    __shared__ int ws[4];
    if (lane == 63) ws[wid] = incl;
    __syncthreads();
    int woff = bsum[blockIdx.x];
    if (wid > 0) woff += ws[0];
    if (wid > 1) woff += ws[1];
    if (wid > 2) woff += ws[2];
    int excl = incl - v + woff;
    if (i < NN) { rowPtr[i] = excl; cursor[i] = excl; }
}

__global__ __launch_bounds__(256) void fill_csr_kernel(
    const int* __restrict__ ei, int* __restrict__ cursor,
    int* __restrict__ csr_src, int E)
{
    int e = blockIdx.x * 256 + threadIdx.x;
    if (e < E) {
        int pos = atomicAdd(&cursor[ei[E + e]], 1);
        csr_src[pos] = ei[e];
    }
}

// ================= fp32 -> fp16 table conversion (x) =================
__global__ __launch_bounds__(256) void cvt_f16_kernel(
    const float* __restrict__ in, ushort* __restrict__ out, int n8)
{
    int i = blockIdx.x * 256 + threadIdx.x;
    if (i >= n8) return;
    const float4* in4 = (const float4*)in;
    float4 a = in4[2 * i], b = in4[2 * i + 1];
    uint4 o;
    o.x = (uint)f2h(a.x) | ((uint)f2h(a.y) << 16);
    o.y = (uint)f2h(a.z) | ((uint)f2h(a.w) << 16);
    o.z = (uint)f2h(b.x) | ((uint)f2h(b.y) << 16);
    o.w = (uint)f2h(b.z) | ((uint)f2h(b.w) << 16);
    ((uint4*)out)[i] = o;
}

// ===== fused: [BN+ReLU prev] + CSR-gather(fp16) + (1+eps)*self -> MFMA MLP + BN stats =====
// 512 thr = 8 waves. Each wave owns a group of 16 consecutive rows:
//   phase 1: per-row EPW-edge-packed gather (fp32 acc) -> fp16 A1 frags (wave-private LDS)
//   phase 2: GEMM1 via mfma_f32_16x16x32_f16 (B frags pre-staged fragment-linear in LDS)
//   phase 3: bias+ReLU -> A2 frags (overlaid on A1 region; in-wave DS ordering, no barrier)
//   phase 4: GEMM2 via MFMA
//   phase 5: bias+ReLU -> fp16 h_out + BN-stat accumulation
template<int F, bool APPLY>
__global__ __launch_bounds__(512, 4) void gin_mlp_kernel(
    const ushort* __restrict__ xin,
    const float* __restrict__ stats_in, const float* __restrict__ g_in,
    const float* __restrict__ be_in,
    const int* __restrict__ rowPtr, const int* __restrict__ csr_src,
    const float* __restrict__ eps_p,
    const float* __restrict__ wa, const float* __restrict__ ba,
    const float* __restrict__ wb, const float* __restrict__ bb,
    ushort* __restrict__ h_out, float* __restrict__ stats_out)
{
    constexpr int C8  = F / 8;        // uint4 chunks per row (16 or 8)
    constexpr int EPW = 64 / C8;      // edges per wave issue (4 or 8)
    constexpr int KC1 = F / 32;       // K-chunks for GEMM1 (4 or 2)
    constexpr int AH  = KC1 * 64 * 8; // halves per wave A region (2048 / 1024)

    __shared__ __align__(16) _Float16 s_B1[F * 64];
    __shared__ __align__(16) _Float16 s_B2[64 * 64];
    __shared__ __align__(16) _Float16 s_A[8][AH];
    __shared__ float s_red[8][64];

    const int tid  = threadIdx.x;
    const int w    = tid >> 6;
    const int lane = tid & 63;

    // ---- stage weights as fp16 MFMA B fragments, fragment-linear ----
    for (int i = tid; i < F * 64; i += 512) {
        int j = i & 7, l = (i >> 3) & 63, t = i >> 9;
        int kc = t >> 2, nt = t & 3;
        int k = kc * 32 + (l >> 4) * 8 + j;
        int n = nt * 16 + (l & 15);
        s_B1[i] = (_Float16)wa[k * 64 + n];
    }
    for (int i = tid; i < 64 * 64; i += 512) {
        int j = i & 7, l = (i >> 3) & 63, t = i >> 9;
        int kc = t >> 2, nt = t & 3;
        int k = kc * 32 + (l >> 4) * 8 + j;
        int n = nt * 16 + (l & 15);
        s_B2[i] = (_Float16)wb[k * 64 + n];
    }

    const int cc  = lane % C8;   // chunk within gathered row
    const int gph = lane / C8;   // edge slot
    const int q   = lane >> 4;   // MFMA quad
    const int mm  = lane & 15;   // MFMA m/n index
    const float eps1 = 1.0f + eps_p[0];

    float ba_val[4], bb_val[4];
    #pragma unroll
    for (int nt = 0; nt < 4; nt++) {
        ba_val[nt] = ba[nt * 16 + mm];
        bb_val[nt] = bb[nt * 16 + mm];
    }

    // BN affine of PREVIOUS layer for this lane's 8 gather columns
    float scv[8], shv[8];
    if (APPLY) {
        int c0 = 8 * cc;
        #pragma unroll
        for (int j = 0; j < 8; j++) {
            float mean = stats_in[c0 + j] * (1.0f / NN);
            float var  = stats_in[64 + c0 + j] * (1.0f / NN) - mean * mean;
            float rstd = rsqrtf(var + BN_EPS);
            float s    = rstd * g_in[c0 + j];
            scv[j] = s;
            shv[j] = be_in[c0 + j] - mean * s;
        }
    }
    __syncthreads();  // weights staged

    float bn_s[4] = {0.f, 0.f, 0.f, 0.f};
    float bn_q[4] = {0.f, 0.f, 0.f, 0.f};
    const uint4* x4 = (const uint4*)xin;
    _Float16* hp   = (_Float16*)h_out;
    _Float16* s_Aw = &s_A[w][0];

    for (int g = blockIdx.x * 8 + w; g < NGROUP; g += gridDim.x * 8) {
        const int row0 = g * 16;

        // ---- phase 1: gather 16 rows into A1 fragments ----
        for (int m = 0; m < 16; m++) {
            int row = row0 + m;
            int beg = rowPtr[row], end = rowPtr[row + 1];
            float a[8];
            #pragma unroll
            for (int j = 0; j < 8; j++) a[j] = 0.0f;
            if (gph == 0) {   // self term
                uint4 v = x4[(size_t)row * C8 + cc];
                float f[8]; unpack8(v, f);
                #pragma unroll
                for (int j = 0; j < 8; j++) {
                    if (APPLY) f[j] = fmaxf(fmaf(f[j], scv[j], shv[j]), 0.0f);
                    a[j] = eps1 * f[j];
                }
            }
            int e  = beg + gph;
            int sn = (e < end) ? csr_src[e] : -1;
            while (sn >= 0) {
                int sc = sn;
                e += EPW;
                sn = (e < end) ? csr_src[e] : -1;
                uint4 v = x4[(size_t)sc * C8 + cc];
                float f[8]; unpack8(v, f);
                #pragma unroll
                for (int j = 0; j < 8; j++) {
                    if (APPLY) f[j] = fmaxf(fmaf(f[j], scv[j], shv[j]), 0.0f);
                    a[j] += f[j];
                }
            }
            #pragma unroll
            for (int off = C8; off < 64; off <<= 1) {
                #pragma unroll
                for (int j = 0; j < 8; j++) a[j] += __shfl_xor(a[j], off, 64);
            }
            if (gph == 0) {
                // lane cc holds k = 8cc..8cc+7 of row m -> frag kc=cc>>2, quad=cc&3
                half8 hv;
                #pragma unroll
                for (int j = 0; j < 8; j++) hv[j] = (_Float16)a[j];
                int slot = (cc >> 2) * 64 + (cc & 3) * 16 + m;
                *(half8*)(s_Aw + (size_t)aswz(slot) * 8) = hv;
            }
        }

        // ---- phase 2: GEMM1 (16 x F) @ (F x 64) ----
        half8 af[KC1];
        #pragma unroll
        for (int kc = 0; kc < KC1; kc++)
            af[kc] = *(const half8*)(s_Aw + (size_t)aswz(kc * 64 + lane) * 8);
        floatx4 acc[4] = {};
        #pragma unroll
        for (int nt = 0; nt < 4; nt++)
            #pragma unroll
            for (int kc = 0; kc < KC1; kc++) {
                half8 bf = *(const half8*)(s_B1 + ((size_t)(kc * 4 + nt) * 64 + lane) * 8);
                acc[nt] = __builtin_amdgcn_mfma_f32_16x16x32_f16(af[kc], bf, acc[nt], 0, 0, 0);
            }

        // ---- phase 3: bias + ReLU -> A2 fragments (overlay A1 region) ----
        // D[row=q*4+r][col=nt*16+mm] becomes A2[m2=row][K2=col]
        #pragma unroll
        for (int nt = 0; nt < 4; nt++)
            #pragma unroll
            for (int r = 0; r < 4; r++) {
                float v = fmaxf(acc[nt][r] + ba_val[nt], 0.0f);
                int slot2 = (nt >> 1) * 64 + ((((nt & 1) << 1) | (mm >> 3)) * 16) + q * 4 + r;
                s_Aw[(size_t)aswz(slot2) * 8 + (mm & 7)] = (_Float16)v;
            }

        // ---- phase 4: GEMM2 (16 x 64) @ (64 x 64) ----
        half8 af2[2];
        #pragma unroll
        for (int kc = 0; kc < 2; kc++)
            af2[kc] = *(const half8*)(s_Aw + (size_t)aswz(kc * 64 + lane) * 8);
        floatx4 acc2[4] = {};
        #pragma unroll
        for (int nt = 0; nt < 4; nt++)
            #pragma unroll
            for (int kc = 0; kc < 2; kc++) {
                half8 bf = *(const half8*)(s_B2 + ((size_t)(kc * 4 + nt) * 64 + lane) * 8);
                acc2[nt] = __builtin_amdgcn_mfma_f32_16x16x32_f16(af2[kc], bf, acc2[nt], 0, 0, 0);
            }

        // ---- phase 5: bias + ReLU -> fp16 h_out + BN partials ----
        #pragma unroll
        for (int nt = 0; nt < 4; nt++)
            #pragma unroll
            for (int r = 0; r < 4; r++) {
                float v = fmaxf(acc2[nt][r] + bb_val[nt], 0.0f);
                bn_s[nt] += v;
                bn_q[nt] += v * v;
                hp[(size_t)(row0 + q * 4 + r) * 64 + nt * 16 + mm] = (_Float16)v;
            }
    }

    // ---- BN stat reduction: quad-shuffle -> cross-wave LDS -> 2 atomics/col/block ----
    #pragma unroll
    for (int nt = 0; nt < 4; nt++) {
        bn_s[nt] += __shfl_xor(bn_s[nt], 16, 64);
        bn_s[nt] += __shfl_xor(bn_s[nt], 32, 64);
        bn_q[nt] += __shfl_xor(bn_q[nt], 16, 64);
        bn_q[nt] += __shfl_xor(bn_q[nt], 32, 64);
    }
    __syncthreads();
    if (lane < 16) {
        #pragma unroll
        for (int nt = 0; nt < 4; nt++) s_red[w][nt * 16 + lane] = bn_s[nt];
    }
    __syncthreads();
    if (w == 0) {
        float s = 0;
        #pragma unroll
        for (int j = 0; j < 8; j++) s += s_red[j][lane];
        atomicAdd(&stats_out[lane], s);
    }
    __syncthreads();
    if (lane < 16) {
        #pragma unroll
        for (int nt = 0; nt < 4; nt++) s_red[w][nt * 16 + lane] = bn_q[nt];
    }
    __syncthreads();
    if (w == 0) {
        float s = 0;
        #pragma unroll
        for (int j = 0; j < 8; j++) s += s_red[j][lane];
        atomicAdd(&stats_out[64 + lane], s);
    }
}

// ---------------- final: BN+ReLU of layer 3 (fp16 h), then (N,64)@(64,10)+b ----------------
__global__ __launch_bounds__(256) void final_linear_kernel(
    const ushort* __restrict__ h, const float* __restrict__ stats,
    const float* __restrict__ g, const float* __restrict__ be,
    const float* __restrict__ w, const float* __restrict__ b,
    float* __restrict__ out)
{
    __shared__ float s_w[640];
    __shared__ float s_b[10];
    __shared__ float s_scale[64];
    __shared__ float s_shift[64];
    for (int i = threadIdx.x; i < 640; i += 256) s_w[i] = w[i];
    if (threadIdx.x < 10) s_b[threadIdx.x] = b[threadIdx.x];
    if (threadIdx.x < 64) {
        int c = threadIdx.x;
        float mean = stats[c] * (1.0f / NN);
        float var  = stats[64 + c] * (1.0f / NN) - mean * mean;
        float rstd = rsqrtf(var + BN_EPS);
        float s    = rstd * g[c];
        s_scale[c] = s;
        s_shift[c] = be[c] - mean * s;
    }
    __syncthreads();
    int row = blockIdx.x * 256 + threadIdx.x;
    if (row >= NN) return;
    float acc[10];
    #pragma unroll
    for (int c = 0; c < 10; c++) acc[c] = s_b[c];
    const uint4* hr = (const uint4*)(h + (size_t)row * 64);
    #pragma unroll
    for (int ch = 0; ch < 8; ch++) {
        uint4 v = hr[ch];
        float f[8]; unpack8(v, f);
        #pragma unroll
        for (int j = 0; j < 8; j++) {
            int k = ch * 8 + j;
            float val = fmaxf(fmaf(f[j], s_scale[k], s_shift[k]), 0.0f);
            #pragma unroll
            for (int c = 0; c < 10; c++) acc[c] = fmaf(val, s_w[k * 10 + c], acc[c]);
        }
    }
    #pragma unroll
    for (int c = 0; c < 10; c++) out[row * 10 + c] = acc[c];
}

extern "C" void kernel_launch(void* const* d_in, const int* in_sizes, int n_in,
                              void* d_out, int out_size, void* d_ws, size_t ws_size,
                              hipStream_t stream)
{
    const float* x  = (const float*)d_in[0];
    const int*   ei = (const int*)d_in[1];
    const int E = in_sizes[1] / 2;

    const float* eps[3]; const float* wa[3]; const float* ba[3];
    const float* wb[3];  const float* bb[3]; const float* g[3]; const float* be[3];
    for (int i = 0; i < 3; i++) {
        int base = 2 + 7 * i;
        eps[i] = (const float*)d_in[base + 0];
        wa[i]  = (const float*)d_in[base + 1];
        ba[i]  = (const float*)d_in[base + 2];
        wb[i]  = (const float*)d_in[base + 3];
        bb[i]  = (const float*)d_in[base + 4];
        g[i]   = (const float*)d_in[base + 5];
        be[i]  = (const float*)d_in[base + 6];
    }
    const float* lin_w = (const float*)d_in[23];
    const float* lin_b = (const float*)d_in[24];
    float* out = (float*)d_out;

    // workspace layout
    const int NB = (NN + 255) / 256;
    char*  base   = (char*)d_ws;
    int*   deg    = (int*)base;               // NN
    int*   rowPtr = deg + NN;                 // NN+1
    int*   cursor = rowPtr + NN + 1;          // NN
    int*   bsum   = cursor + NN;              // 256
    int*   csrsrc = bsum + 256;               // E
    size_t ioff   = (char*)(csrsrc + E) - base;
    ushort* xhf   = (ushort*)(base + ((ioff + 15) & ~(size_t)15));  // NN*128
    ushort* hA    = xhf + (size_t)NN * 128;   // NN*64
    ushort* hB    = hA + (size_t)NN * 64;     // NN*64
    float* stats  = (float*)(hB + (size_t)NN * 64);  // 3*128

    // ---- CSR build + x conversion ----
    hipMemsetAsync(deg, 0, NN * sizeof(int), stream);
    hipMemsetAsync(stats, 0, 3 * 128 * sizeof(float), stream);
    hist_kernel<<<(E + 255) / 256, 256, 0, stream>>>(ei, deg, E);
    cvt_f16_kernel<<<(NN * 128 / 8 + 255) / 256, 256, 0, stream>>>(x, xhf, NN * 128 / 8);
    bsum_kernel<<<NB, 256, 0, stream>>>(deg, bsum);
    bscan_kernel<<<1, 256, 0, stream>>>(bsum, rowPtr, NB, E);
    scan_apply_kernel<<<NB, 256, 0, stream>>>(deg, bsum, rowPtr, cursor);
    fill_csr_kernel<<<(E + 255) / 256, 256, 0, stream>>>(ei, cursor, csrsrc, E);

    const int GRID = (NGROUP + 7) / 8;   // 391: one 16-row group per wave

    // ---- layer 1 (F=128) ----
    gin_mlp_kernel<128, false><<<GRID, 512, 0, stream>>>(
        xhf, nullptr, nullptr, nullptr, rowPtr, csrsrc, eps[0],
        wa[0], ba[0], wb[0], bb[0], hA, stats);
    // ---- layer 2 (F=64, BN1+ReLU fused into gather) ----
    gin_mlp_kernel<64, true><<<GRID, 512, 0, stream>>>(
        hA, stats, g[0], be[0], rowPtr, csrsrc, eps[1],
        wa[1], ba[1], wb[1], bb[1], hB, stats + 128);
    // ---- layer 3 (F=64, BN2+ReLU fused) ----
    gin_mlp_kernel<64, true><<<GRID, 512, 0, stream>>>(
        hB, stats + 128, g[1], be[1], rowPtr, csrsrc, eps[2],
        wa[2], ba[2], wb[2], bb[2], hA, stats + 256);
    // ---- final linear with BN3+ReLU fused ----
    final_linear_kernel<<<(NN + 255) / 256, 256, 0, stream>>>(
        hA, stats + 256, g[2], be[2], lin_w, lin_b, out);
}

// Round 7
// 400.533 us; speedup vs baseline: 1.1237x; 1.0105x over previous
//
#include <hip/hip_runtime.h>
#include <hip/hip_fp16.h>

#define NN 50000
#define NGROUP 3125   // NN / 16 (exact)
#define BN_EPS 1e-5f

typedef unsigned int uint;
typedef unsigned short ushort;
typedef _Float16 half8 __attribute__((ext_vector_type(8)));
typedef float floatx4 __attribute__((ext_vector_type(4)));

__device__ __forceinline__ int aswz(int slot) { return slot ^ ((slot >> 4) & 7); }

__device__ __forceinline__ float h_lo(uint u) {
    return __half2float(__ushort_as_half((ushort)(u & 0xFFFFu)));
}
__device__ __forceinline__ float h_hi(uint u) {
    return __half2float(__ushort_as_half((ushort)(u >> 16)));
}
__device__ __forceinline__ void unpack8(uint4 v, float* f) {
    f[0] = h_lo(v.x); f[1] = h_hi(v.x);
    f[2] = h_lo(v.y); f[3] = h_hi(v.y);
    f[4] = h_lo(v.z); f[5] = h_hi(v.z);
    f[6] = h_lo(v.w); f[7] = h_hi(v.w);
}
__device__ __forceinline__ ushort f2h(float x) {
    return __half_as_ushort(__float2half_rn(x));
}

// ================= CSR build (by dst) =================
__global__ __launch_bounds__(256) void hist_kernel(
    const int* __restrict__ ei, int* __restrict__ deg, int E)
{
    int e = blockIdx.x * 256 + threadIdx.x;
    if (e < E) atomicAdd(&deg[ei[E + e]], 1);
}

__global__ __launch_bounds__(256) void bsum_kernel(
    const int* __restrict__ deg, int* __restrict__ bsum)
{
    int i = blockIdx.x * 256 + threadIdx.x;
    int v = (i < NN) ? deg[i] : 0;
    #pragma unroll
    for (int off = 32; off >= 1; off >>= 1) v += __shfl_down(v, off, 64);
    __shared__ int ws[4];
    int lane = threadIdx.x & 63, wid = threadIdx.x >> 6;
    if (lane == 0) ws[wid] = v;
    __syncthreads();
    if (threadIdx.x == 0) bsum[blockIdx.x] = ws[0] + ws[1] + ws[2] + ws[3];
}

__global__ __launch_bounds__(256) void bscan_kernel(
    int* __restrict__ bsum, int* __restrict__ rowPtr, int NB, int E)
{
    int lane = threadIdx.x & 63, wid = threadIdx.x >> 6;
    int v = (threadIdx.x < NB) ? bsum[threadIdx.x] : 0;
    int incl = v;
    #pragma unroll
    for (int off = 1; off < 64; off <<= 1) {
        int t = __shfl_up(incl, off, 64);
        if (lane >= off) incl += t;
    }
    __shared__ int ws[4];
    if (lane == 63) ws[wid] = incl;
    __syncthreads();
    int woff = 0;
    if (wid > 0) woff += ws[0];
    if (wid > 1) woff += ws[1];
    if (wid > 2) woff += ws[2];
    if (threadIdx.x < NB) bsum[threadIdx.x] = incl - v + woff;
    if (threadIdx.x == 0) rowPtr[NN] = E;
}

__global__ __launch_bounds__(256) void scan_apply_kernel(
    const int* __restrict__ deg, const int* __restrict__ bsum,
    int* __restrict__ rowPtr, int* __restrict__ cursor)
{
    int i = blockIdx.x * 256 + threadIdx.x;
    int lane = threadIdx.x & 63, wid = threadIdx.x >> 6;
    int v = (i < NN) ? deg[i] : 0;
    int incl = v;
    #pragma unroll
    for (int off = 1; off < 64; off <<= 1) {
        int t = __shfl_up(incl, off, 64);
        if (lane >= off) incl += t;
    }
    __shared__ int ws[4];
    if (lane == 63) ws[wid] = incl;
    __syncthreads();
    int woff = bsum[blockIdx.x];
    if (wid > 0) woff += ws[0];
    if (wid > 1) woff += ws[1];
    if (wid > 2) woff += ws[2];
    int excl = incl - v + woff;
    if (i < NN) { rowPtr[i] = excl; cursor[i] = excl; }
}

__global__ __launch_bounds__(256) void fill_csr_kernel(
    const int* __restrict__ ei, int* __restrict__ cursor,
    int* __restrict__ csr_src, int E)
{
    int e = blockIdx.x * 256 + threadIdx.x;
    if (e < E) {
        int pos = atomicAdd(&cursor[ei[E + e]], 1);
        csr_src[pos] = ei[e];
    }
}

// ================= fp32 -> fp16 table conversion (x) =================
__global__ __launch_bounds__(256) void cvt_f16_kernel(
    const float* __restrict__ in, ushort* __restrict__ out, int n8)
{
    int i = blockIdx.x * 256 + threadIdx.x;
    if (i >= n8) return;
    const float4* in4 = (const float4*)in;
    float4 a = in4[2 * i], b = in4[2 * i + 1];
    uint4 o;
    o.x = (uint)f2h(a.x) | ((uint)f2h(a.y) << 16);
    o.y = (uint)f2h(a.z) | ((uint)f2h(a.w) << 16);
    o.z = (uint)f2h(b.x) | ((uint)f2h(b.y) << 16);
    o.w = (uint)f2h(b.z) | ((uint)f2h(b.w) << 16);
    ((uint4*)out)[i] = o;
}

// ===== fused: [BN+ReLU prev] + CSR-gather(fp16) + (1+eps)*self -> MFMA MLP + BN stats =====
// 512 thr = 8 waves. Each wave owns a group of 16 consecutive rows:
//   phase 1: 2-row-interleaved, value-prefetched gather -> fp16 A1 frags (wave-private LDS)
//   phase 2: GEMM1 via mfma_f32_16x16x32_f16 (B frags fragment-linear in LDS)
//   phase 3: bias+ReLU -> A2 frags (overlaid; in-wave DS ordering, no barrier)
//   phase 4: GEMM2 via MFMA
//   phase 5: bias+ReLU -> LDS tile -> coalesced b128 stores + BN-stat accumulation
template<int F, bool APPLY>
__global__ __launch_bounds__(512, 4) void gin_mlp_kernel(
    const ushort* __restrict__ xin,
    const float* __restrict__ stats_in, const float* __restrict__ g_in,
    const float* __restrict__ be_in,
    const int* __restrict__ rowPtr, const int* __restrict__ csr_src,
    const float* __restrict__ eps_p,
    const float* __restrict__ wa, const float* __restrict__ ba,
    const float* __restrict__ wb, const float* __restrict__ bb,
    ushort* __restrict__ h_out, float* __restrict__ stats_out)
{
    constexpr int C8  = F / 8;        // uint4 chunks per row (16 or 8)
    constexpr int EPW = 64 / C8;      // edges per wave issue (4 or 8)
    constexpr int KC1 = F / 32;       // K-chunks for GEMM1 (4 or 2)
    constexpr int AH  = KC1 * 64 * 8; // halves per wave A region (2048 / 1024)

    __shared__ __align__(16) _Float16 s_B1[F * 64];
    __shared__ __align__(16) _Float16 s_B2[64 * 64];
    __shared__ __align__(16) _Float16 s_A[8][AH];
    __shared__ float s_red[8][64];

    const int tid  = threadIdx.x;
    const int w    = tid >> 6;
    const int lane = tid & 63;

    // ---- stage weights as fp16 MFMA B fragments, fragment-linear ----
    for (int i = tid; i < F * 64; i += 512) {
        int j = i & 7, l = (i >> 3) & 63, t = i >> 9;
        int kc = t >> 2, nt = t & 3;
        int k = kc * 32 + (l >> 4) * 8 + j;
        int n = nt * 16 + (l & 15);
        s_B1[i] = (_Float16)wa[k * 64 + n];
    }
    for (int i = tid; i < 64 * 64; i += 512) {
        int j = i & 7, l = (i >> 3) & 63, t = i >> 9;
        int kc = t >> 2, nt = t & 3;
        int k = kc * 32 + (l >> 4) * 8 + j;
        int n = nt * 16 + (l & 15);
        s_B2[i] = (_Float16)wb[k * 64 + n];
    }

    const int cc  = lane % C8;   // chunk within gathered row
    const int gph = lane / C8;   // edge slot
    const int q   = lane >> 4;   // MFMA quad
    const int mm  = lane & 15;   // MFMA m/n index
    const float eps1 = 1.0f + eps_p[0];

    float ba_val[4], bb_val[4];
    #pragma unroll
    for (int nt = 0; nt < 4; nt++) {
        ba_val[nt] = ba[nt * 16 + mm];
        bb_val[nt] = bb[nt * 16 + mm];
    }

    // BN affine of PREVIOUS layer for this lane's 8 gather columns
    float scv[8], shv[8];
    if (APPLY) {
        int c0 = 8 * cc;
        #pragma unroll
        for (int j = 0; j < 8; j++) {
            float mean = stats_in[c0 + j] * (1.0f / NN);
            float var  = stats_in[64 + c0 + j] * (1.0f / NN) - mean * mean;
            float rstd = rsqrtf(var + BN_EPS);
            float s    = rstd * g_in[c0 + j];
            scv[j] = s;
            shv[j] = be_in[c0 + j] - mean * s;
        }
    }
    __syncthreads();  // weights staged

    float bn_s[4] = {0.f, 0.f, 0.f, 0.f};
    float bn_q[4] = {0.f, 0.f, 0.f, 0.f};
    const uint4* x4 = (const uint4*)xin;
    _Float16* hp   = (_Float16*)h_out;
    _Float16* s_Aw = &s_A[w][0];

    for (int g = blockIdx.x * 8 + w; g < NGROUP; g += gridDim.x * 8) {
        const int row0 = g * 16;

        // ---- phase 1: gather 16 rows (2 interleaved at a time, value-prefetched) ----
        for (int m = 0; m < 16; m += 2) {
            const int rowA = row0 + m, rowB = row0 + m + 1;
            int eA = rowPtr[rowA] + gph, endA = rowPtr[rowA + 1];
            int eB = rowPtr[rowB] + gph, endB = rowPtr[rowB + 1];
            float aA[8], aB[8];
            #pragma unroll
            for (int j = 0; j < 8; j++) { aA[j] = 0.0f; aB[j] = 0.0f; }

            if (gph == 0) {   // self terms
                uint4 vsA = x4[(size_t)rowA * C8 + cc];
                uint4 vsB = x4[(size_t)rowB * C8 + cc];
                float fA[8], fB[8];
                unpack8(vsA, fA); unpack8(vsB, fB);
                #pragma unroll
                for (int j = 0; j < 8; j++) {
                    if (APPLY) {
                        fA[j] = fmaxf(fmaf(fA[j], scv[j], shv[j]), 0.0f);
                        fB[j] = fmaxf(fmaf(fB[j], scv[j], shv[j]), 0.0f);
                    }
                    aA[j] = eps1 * fA[j];
                    aB[j] = eps1 * fB[j];
                }
            }

            int sA = (eA < endA) ? csr_src[eA] : -1;
            int sB = (eB < endB) ? csr_src[eB] : -1;
            uint4 vA, vB;
            if (sA >= 0) vA = x4[(size_t)sA * C8 + cc];
            if (sB >= 0) vB = x4[(size_t)sB * C8 + cc];

            while (sA >= 0 || sB >= 0) {
                int nA = -1, nB = -1;
                if (sA >= 0) { eA += EPW; nA = (eA < endA) ? csr_src[eA] : -1; }
                if (sB >= 0) { eB += EPW; nB = (eB < endB) ? csr_src[eB] : -1; }
                uint4 pA, pB;
                if (nA >= 0) pA = x4[(size_t)nA * C8 + cc];
                if (nB >= 0) pB = x4[(size_t)nB * C8 + cc];
                if (sA >= 0) {
                    float f[8]; unpack8(vA, f);
                    #pragma unroll
                    for (int j = 0; j < 8; j++) {
                        if (APPLY) f[j] = fmaxf(fmaf(f[j], scv[j], shv[j]), 0.0f);
                        aA[j] += f[j];
                    }
                }
                if (sB >= 0) {
                    float f[8]; unpack8(vB, f);
                    #pragma unroll
                    for (int j = 0; j < 8; j++) {
                        if (APPLY) f[j] = fmaxf(fmaf(f[j], scv[j], shv[j]), 0.0f);
                        aB[j] += f[j];
                    }
                }
                sA = nA; vA = pA;
                sB = nB; vB = pB;
            }

            // reduce across edge slots (both rows)
            #pragma unroll
            for (int off = C8; off < 64; off <<= 1) {
                #pragma unroll
                for (int j = 0; j < 8; j++) {
                    aA[j] += __shfl_xor(aA[j], off, 64);
                    aB[j] += __shfl_xor(aB[j], off, 64);
                }
            }
            if (gph == 0) {
                // lane cc holds k = 8cc..8cc+7 -> frag kc=cc>>2, quad=cc&3
                half8 hA, hB;
                #pragma unroll
                for (int j = 0; j < 8; j++) { hA[j] = (_Float16)aA[j]; hB[j] = (_Float16)aB[j]; }
                int slotA = (cc >> 2) * 64 + (cc & 3) * 16 + m;
                *(half8*)(s_Aw + (size_t)aswz(slotA) * 8) = hA;
                *(half8*)(s_Aw + (size_t)aswz(slotA + 1) * 8) = hB;
            }
        }

        // ---- phase 2: GEMM1 (16 x F) @ (F x 64) ----
        half8 af[KC1];
        #pragma unroll
        for (int kc = 0; kc < KC1; kc++)
            af[kc] = *(const half8*)(s_Aw + (size_t)aswz(kc * 64 + lane) * 8);
        floatx4 acc[4] = {};
        #pragma unroll
        for (int nt = 0; nt < 4; nt++)
            #pragma unroll
            for (int kc = 0; kc < KC1; kc++) {
                half8 bf = *(const half8*)(s_B1 + ((size_t)(kc * 4 + nt) * 64 + lane) * 8);
                acc[nt] = __builtin_amdgcn_mfma_f32_16x16x32_f16(af[kc], bf, acc[nt], 0, 0, 0);
            }

        // ---- phase 3: bias + ReLU -> A2 fragments (overlay A1 region) ----
        #pragma unroll
        for (int nt = 0; nt < 4; nt++)
            #pragma unroll
            for (int r = 0; r < 4; r++) {
                float v = fmaxf(acc[nt][r] + ba_val[nt], 0.0f);
                int slot2 = (nt >> 1) * 64 + ((((nt & 1) << 1) | (mm >> 3)) * 16) + q * 4 + r;
                s_Aw[(size_t)aswz(slot2) * 8 + (mm & 7)] = (_Float16)v;
            }

        // ---- phase 4: GEMM2 (16 x 64) @ (64 x 64) ----
        half8 af2[2];
        #pragma unroll
        for (int kc = 0; kc < 2; kc++)
            af2[kc] = *(const half8*)(s_Aw + (size_t)aswz(kc * 64 + lane) * 8);
        floatx4 acc2[4] = {};
        #pragma unroll
        for (int nt = 0; nt < 4; nt++)
            #pragma unroll
            for (int kc = 0; kc < 2; kc++) {
                half8 bf = *(const half8*)(s_B2 + ((size_t)(kc * 4 + nt) * 64 + lane) * 8);
                acc2[nt] = __builtin_amdgcn_mfma_f32_16x16x32_f16(af2[kc], bf, acc2[nt], 0, 0, 0);
            }

        // ---- phase 5: bias + ReLU -> LDS row-major tile -> coalesced stores ----
        #pragma unroll
        for (int nt = 0; nt < 4; nt++)
            #pragma unroll
            for (int r = 0; r < 4; r++) {
                float v = fmaxf(acc2[nt][r] + bb_val[nt], 0.0f);
                bn_s[nt] += v;
                bn_q[nt] += v * v;
                s_Aw[(q * 4 + r) * 64 + nt * 16 + mm] = (_Float16)v;  // [m][n]
            }
        // in-wave DS ordering: writes above complete before reads below
        {
            half8 t0 = *(const half8*)(s_Aw + lane * 8);
            half8 t1 = *(const half8*)(s_Aw + 512 + lane * 8);
            half8* dst = (half8*)(hp + (size_t)row0 * 64);
            dst[lane] = t0;
            dst[64 + lane] = t1;
        }
    }

    // ---- BN stat reduction: quad-shuffle -> cross-wave LDS -> 2 atomics/col/block ----
    #pragma unroll
    for (int nt = 0; nt < 4; nt++) {
        bn_s[nt] += __shfl_xor(bn_s[nt], 16, 64);
        bn_s[nt] += __shfl_xor(bn_s[nt], 32, 64);
        bn_q[nt] += __shfl_xor(bn_q[nt], 16, 64);
        bn_q[nt] += __shfl_xor(bn_q[nt], 32, 64);
    }
    __syncthreads();
    if (lane < 16) {
        #pragma unroll
        for (int nt = 0; nt < 4; nt++) s_red[w][nt * 16 + lane] = bn_s[nt];
    }
    __syncthreads();
    if (w == 0) {
        float s = 0;
        #pragma unroll
        for (int j = 0; j < 8; j++) s += s_red[j][lane];
        atomicAdd(&stats_out[lane], s);
    }
    __syncthreads();
    if (lane < 16) {
        #pragma unroll
        for (int nt = 0; nt < 4; nt++) s_red[w][nt * 16 + lane] = bn_q[nt];
    }
    __syncthreads();
    if (w == 0) {
        float s = 0;
        #pragma unroll
        for (int j = 0; j < 8; j++) s += s_red[j][lane];
        atomicAdd(&stats_out[64 + lane], s);
    }
}

// ---------------- final: BN+ReLU of layer 3 (fp16 h), then (N,64)@(64,10)+b ----------------
__global__ __launch_bounds__(256) void final_linear_kernel(
    const ushort* __restrict__ h, const float* __restrict__ stats,
    const float* __restrict__ g, const float* __restrict__ be,
    const float* __restrict__ w, const float* __restrict__ b,
    float* __restrict__ out)
{
    __shared__ float s_w[640];
    __shared__ float s_b[10];
    __shared__ float s_scale[64];
    __shared__ float s_shift[64];
    for (int i = threadIdx.x; i < 640; i += 256) s_w[i] = w[i];
    if (threadIdx.x < 10) s_b[threadIdx.x] = b[threadIdx.x];
    if (threadIdx.x < 64) {
        int c = threadIdx.x;
        float mean = stats[c] * (1.0f / NN);
        float var  = stats[64 + c] * (1.0f / NN) - mean * mean;
        float rstd = rsqrtf(var + BN_EPS);
        float s    = rstd * g[c];
        s_scale[c] = s;
        s_shift[c] = be[c] - mean * s;
    }
    __syncthreads();
    int row = blockIdx.x * 256 + threadIdx.x;
    if (row >= NN) return;
    float acc[10];
    #pragma unroll
    for (int c = 0; c < 10; c++) acc[c] = s_b[c];
    const uint4* hr = (const uint4*)(h + (size_t)row * 64);
    #pragma unroll
    for (int ch = 0; ch < 8; ch++) {
        uint4 v = hr[ch];
        float f[8]; unpack8(v, f);
        #pragma unroll
        for (int j = 0; j < 8; j++) {
            int k = ch * 8 + j;
            float val = fmaxf(fmaf(f[j], s_scale[k], s_shift[k]), 0.0f);
            #pragma unroll
            for (int c = 0; c < 10; c++) acc[c] = fmaf(val, s_w[k * 10 + c], acc[c]);
        }
    }
    #pragma unroll
    for (int c = 0; c < 10; c++) out[row * 10 + c] = acc[c];
}

extern "C" void kernel_launch(void* const* d_in, const int* in_sizes, int n_in,
                              void* d_out, int out_size, void* d_ws, size_t ws_size,
                              hipStream_t stream)
{
    const float* x  = (const float*)d_in[0];
    const int*   ei = (const int*)d_in[1];
    const int E = in_sizes[1] / 2;

    const float* eps[3]; const float* wa[3]; const float* ba[3];
    const float* wb[3];  const float* bb[3]; const float* g[3]; const float* be[3];
    for (int i = 0; i < 3; i++) {
        int base = 2 + 7 * i;
        eps[i] = (const float*)d_in[base + 0];
        wa[i]  = (const float*)d_in[base + 1];
        ba[i]  = (const float*)d_in[base + 2];
        wb[i]  = (const float*)d_in[base + 3];
        bb[i]  = (const float*)d_in[base + 4];
        g[i]   = (const float*)d_in[base + 5];
        be[i]  = (const float*)d_in[base + 6];
    }
    const float* lin_w = (const float*)d_in[23];
    const float* lin_b = (const float*)d_in[24];
    float* out = (float*)d_out;

    // workspace layout
    const int NB = (NN + 255) / 256;
    char*  base   = (char*)d_ws;
    int*   deg    = (int*)base;               // NN
    int*   rowPtr = deg + NN;                 // NN+1
    int*   cursor = rowPtr + NN + 1;          // NN
    int*   bsum   = cursor + NN;              // 256
    int*   csrsrc = bsum + 256;               // E
    size_t ioff   = (char*)(csrsrc + E) - base;
    ushort* xhf   = (ushort*)(base + ((ioff + 15) & ~(size_t)15));  // NN*128
    ushort* hA    = xhf + (size_t)NN * 128;   // NN*64
    ushort* hB    = hA + (size_t)NN * 64;     // NN*64
    float* stats  = (float*)(hB + (size_t)NN * 64);  // 3*128

    // ---- CSR build + x conversion ----
    hipMemsetAsync(deg, 0, NN * sizeof(int), stream);
    hipMemsetAsync(stats, 0, 3 * 128 * sizeof(float), stream);
    hist_kernel<<<(E + 255) / 256, 256, 0, stream>>>(ei, deg, E);
    cvt_f16_kernel<<<(NN * 128 / 8 + 255) / 256, 256, 0, stream>>>(x, xhf, NN * 128 / 8);
    bsum_kernel<<<NB, 256, 0, stream>>>(deg, bsum);
    bscan_kernel<<<1, 256, 0, stream>>>(bsum, rowPtr, NB, E);
    scan_apply_kernel<<<NB, 256, 0, stream>>>(deg, bsum, rowPtr, cursor);
    fill_csr_kernel<<<(E + 255) / 256, 256, 0, stream>>>(ei, cursor, csrsrc, E);

    const int GRID = (NGROUP + 7) / 8;   // 391: one 16-row group per wave

    // ---- layer 1 (F=128) ----
    gin_mlp_kernel<128, false><<<GRID, 512, 0, stream>>>(
        xhf, nullptr, nullptr, nullptr, rowPtr, csrsrc, eps[0],
        wa[0], ba[0], wb[0], bb[0], hA, stats);
    // ---- layer 2 (F=64, BN1+ReLU fused into gather) ----
    gin_mlp_kernel<64, true><<<GRID, 512, 0, stream>>>(
        hA, stats, g[0], be[0], rowPtr, csrsrc, eps[1],
        wa[1], ba[1], wb[1], bb[1], hB, stats + 128);
    // ---- layer 3 (F=64, BN2+ReLU fused) ----
    gin_mlp_kernel<64, true><<<GRID, 512, 0, stream>>>(
        hB, stats + 128, g[1], be[1], rowPtr, csrsrc, eps[2],
        wa[2], ba[2], wb[2], bb[2], hA, stats + 256);
    // ---- final linear with BN3+ReLU fused ----
    final_linear_kernel<<<(NN + 255) / 256, 256, 0, stream>>>(
        hA, stats + 256, g[2], be[2], lin_w, lin_b, out);
}

// Round 8
// 368.148 us; speedup vs baseline: 1.2226x; 1.0880x over previous
//
#include <hip/hip_runtime.h>
#include <hip/hip_fp16.h>

#define NN 50000
#define NGROUP 3125   // NN / 16 (exact)
#define BN_EPS 1e-5f

typedef unsigned int uint;
typedef unsigned short ushort;
typedef _Float16 half8 __attribute__((ext_vector_type(8)));
typedef float floatx4 __attribute__((ext_vector_type(4)));

__device__ __forceinline__ int aswz(int slot) { return slot ^ ((slot >> 4) & 7); }

__device__ __forceinline__ float h_lo(uint u) {
    return __half2float(__ushort_as_half((ushort)(u & 0xFFFFu)));
}
__device__ __forceinline__ float h_hi(uint u) {
    return __half2float(__ushort_as_half((ushort)(u >> 16)));
}
__device__ __forceinline__ void unpack8(uint4 v, float* f) {
    f[0] = h_lo(v.x); f[1] = h_hi(v.x);
    f[2] = h_lo(v.y); f[3] = h_hi(v.y);
    f[4] = h_lo(v.z); f[5] = h_hi(v.z);
    f[6] = h_lo(v.w); f[7] = h_hi(v.w);
}

// ================= CSR build (by dst) =================
__global__ __launch_bounds__(256) void hist_kernel(
    const int* __restrict__ ei, int* __restrict__ deg, int E)
{
    int e = blockIdx.x * 256 + threadIdx.x;
    if (e < E) atomicAdd(&deg[ei[E + e]], 1);
}

__global__ __launch_bounds__(256) void bsum_kernel(
    const int* __restrict__ deg, int* __restrict__ bsum)
{
    int i = blockIdx.x * 256 + threadIdx.x;
    int v = (i < NN) ? deg[i] : 0;
    #pragma unroll
    for (int off = 32; off >= 1; off >>= 1) v += __shfl_down(v, off, 64);
    __shared__ int ws[4];
    int lane = threadIdx.x & 63, wid = threadIdx.x >> 6;
    if (lane == 0) ws[wid] = v;
    __syncthreads();
    if (threadIdx.x == 0) bsum[blockIdx.x] = ws[0] + ws[1] + ws[2] + ws[3];
}

__global__ __launch_bounds__(256) void bscan_kernel(
    int* __restrict__ bsum, int* __restrict__ rowPtr, int NB, int E)
{
    int lane = threadIdx.x & 63, wid = threadIdx.x >> 6;
    int v = (threadIdx.x < NB) ? bsum[threadIdx.x] : 0;
    int incl = v;
    #pragma unroll
    for (int off = 1; off < 64; off <<= 1) {
        int t = __shfl_up(incl, off, 64);
        if (lane >= off) incl += t;
    }
    __shared__ int ws[4];
    if (lane == 63) ws[wid] = incl;
    __syncthreads();
    int woff = 0;
    if (wid > 0) woff += ws[0];
    if (wid > 1) woff += ws[1];
    if (wid > 2) woff += ws[2];
    if (threadIdx.x < NB) bsum[threadIdx.x] = incl - v + woff;
    if (threadIdx.x == 0) rowPtr[NN] = E;
}

__global__ __launch_bounds__(256) void scan_apply_kernel(
    const int* __restrict__ deg, const int* __restrict__ bsum,
    int* __restrict__ rowPtr, int* __restrict__ cursor)
{
    int i = blockIdx.x * 256 + threadIdx.x;
    int lane = threadIdx.x & 63, wid = threadIdx.x >> 6;
    int v = (i < NN) ? deg[i] : 0;
    int incl = v;
    #pragma unroll
    for (int off = 1; off < 64; off <<= 1) {
        int t = __shfl_up(incl, off, 64);
        if (lane >= off) incl += t;
    }
    __shared__ int ws[4];
    if (lane == 63) ws[wid] = incl;
    __syncthreads();
    int woff = bsum[blockIdx.x];
    if (wid > 0) woff += ws[0];
    if (wid > 1) woff += ws[1];
    if (wid > 2) woff += ws[2];
    int excl = incl - v + woff;
    if (i < NN) { rowPtr[i] = excl; cursor[i] = excl; }
}

__global__ __launch_bounds__(256) void fill_csr_kernel(
    const int* __restrict__ ei, int* __restrict__ cursor,
    int* __restrict__ csr_src, int E)
{
    int e = blockIdx.x * 256 + threadIdx.x;
    if (e < E) {
        int pos = atomicAdd(&cursor[ei[E + e]], 1);
        csr_src[pos] = ei[e];
    }
}

// ======== proj: y = W_a^T * z, z = BNReLU(h_in) [APPLY] or cvt(x) [layer 1] ========
// 256 thr = 4 waves, one 16-row group per wave. Dense MFMA, coalesced in/out.
template<int FIN, bool APPLY>
__global__ __launch_bounds__(256, 4) void proj_kernel(
    const void* __restrict__ in_v,
    const float* __restrict__ stats_in, const float* __restrict__ g_in,
    const float* __restrict__ be_in,
    const float* __restrict__ wa,
    ushort* __restrict__ y_out)
{
    constexpr int KC = FIN / 32;
    __shared__ __align__(16) _Float16 s_B[FIN * 64];
    __shared__ __align__(16) _Float16 s_Y[4][1024];

    const int tid = threadIdx.x, w = tid >> 6, lane = tid & 63;
    const int q = lane >> 4, mm = lane & 15;

    // stage W_a as fp16 B fragments (fragment-linear)
    for (int i = tid; i < FIN * 64; i += 256) {
        int j = i & 7, l = (i >> 3) & 63, t = i >> 9;
        int kc = t >> 2, nt = t & 3;
        int k = kc * 32 + (l >> 4) * 8 + j;
        int n = nt * 16 + (l & 15);
        s_B[i] = (_Float16)wa[k * 64 + n];
    }

    // BN affine of previous layer for this lane's A-frag columns (k = kc*32+q*8+j)
    float scv[2][8], shv[2][8];
    if (APPLY) {
        #pragma unroll
        for (int kc = 0; kc < 2; kc++)
            #pragma unroll
            for (int j = 0; j < 8; j++) {
                int c = kc * 32 + q * 8 + j;
                float mean = stats_in[c] * (1.0f / NN);
                float var  = stats_in[64 + c] * (1.0f / NN) - mean * mean;
                float rstd = rsqrtf(var + BN_EPS);
                float s    = rstd * g_in[c];
                scv[kc][j] = s;
                shv[kc][j] = be_in[c] - mean * s;
            }
    }
    __syncthreads();

    int g = blockIdx.x * 4 + w;
    if (g >= NGROUP) return;   // no barriers beyond this point
    const int row = g * 16 + mm;

    half8 af[KC];
    if (FIN == 128) {
        const float* xin = (const float*)in_v;
        #pragma unroll
        for (int kc = 0; kc < KC; kc++) {
            const float* p = xin + (size_t)row * 128 + kc * 32 + q * 8;
            float4 a = *(const float4*)p;
            float4 b = *(const float4*)(p + 4);
            half8 hv;
            hv[0] = (_Float16)a.x; hv[1] = (_Float16)a.y;
            hv[2] = (_Float16)a.z; hv[3] = (_Float16)a.w;
            hv[4] = (_Float16)b.x; hv[5] = (_Float16)b.y;
            hv[6] = (_Float16)b.z; hv[7] = (_Float16)b.w;
            af[kc] = hv;
        }
    } else {
        const ushort* hin = (const ushort*)in_v;
        #pragma unroll
        for (int kc = 0; kc < KC; kc++) {
            uint4 vv = *(const uint4*)(hin + (size_t)row * 64 + kc * 32 + q * 8);
            float f[8]; unpack8(vv, f);
            half8 hv;
            #pragma unroll
            for (int j = 0; j < 8; j++) {
                float z = APPLY ? fmaxf(fmaf(f[j], scv[kc][j], shv[kc][j]), 0.0f) : f[j];
                hv[j] = (_Float16)z;
            }
            af[kc] = hv;
        }
    }

    floatx4 acc[4] = {};
    #pragma unroll
    for (int nt = 0; nt < 4; nt++)
        #pragma unroll
        for (int kc = 0; kc < KC; kc++) {
            half8 bf = *(const half8*)(s_B + ((size_t)(kc * 4 + nt) * 64 + lane) * 8);
            acc[nt] = __builtin_amdgcn_mfma_f32_16x16x32_f16(af[kc], bf, acc[nt], 0, 0, 0);
        }

    // epilogue: transpose via wave-private LDS -> coalesced stores (no bias/relu here)
    _Float16* s_Yw = &s_Y[w][0];
    #pragma unroll
    for (int nt = 0; nt < 4; nt++)
        #pragma unroll
        for (int r = 0; r < 4; r++)
            s_Yw[(q * 4 + r) * 64 + nt * 16 + mm] = (_Float16)acc[nt][r];
    half8 t0 = *(const half8*)(s_Yw + lane * 8);
    half8 t1 = *(const half8*)(s_Yw + 512 + lane * 8);
    half8* dst = (half8*)((_Float16*)y_out + (size_t)g * 1024);
    dst[lane] = t0;
    dst[64 + lane] = t1;
}

// ======== gather: s=(1+eps)y_self + sum y_nbr; t=relu(s+b_a); h=relu(W_b t + b_b) ========
// 512 thr = 8 waves, one 16-row group per wave; 4-row interleaved value-prefetched gather.
__global__ __launch_bounds__(512, 4) void gin_gather_kernel(
    const ushort* __restrict__ y,
    const int* __restrict__ rowPtr, const int* __restrict__ csr_src,
    const float* __restrict__ eps_p, const float* __restrict__ ba,
    const float* __restrict__ wb, const float* __restrict__ bb,
    ushort* __restrict__ h_out, float* __restrict__ stats_out)
{
    __shared__ __align__(16) _Float16 s_B2[64 * 64];
    __shared__ __align__(16) _Float16 s_A[8][1024];
    __shared__ float s_red[8][64];

    const int tid = threadIdx.x, w = tid >> 6, lane = tid & 63;
    const int cc = lane & 7, gph = lane >> 3;
    const int q = lane >> 4, mm = lane & 15;

    for (int i = tid; i < 64 * 64; i += 512) {
        int j = i & 7, l = (i >> 3) & 63, t = i >> 9;
        int kc = t >> 2, nt = t & 3;
        int k = kc * 32 + (l >> 4) * 8 + j;
        int n = nt * 16 + (l & 15);
        s_B2[i] = (_Float16)wb[k * 64 + n];
    }

    const float eps1 = 1.0f + eps_p[0];
    float bav[8];
    #pragma unroll
    for (int j = 0; j < 8; j++) bav[j] = ba[8 * cc + j];
    float bbv[4];
    #pragma unroll
    for (int nt = 0; nt < 4; nt++) bbv[nt] = bb[nt * 16 + mm];
    __syncthreads();

    float bn_s[4] = {0.f, 0.f, 0.f, 0.f};
    float bn_q[4] = {0.f, 0.f, 0.f, 0.f};
    const uint4* y4 = (const uint4*)y;
    const int g = blockIdx.x * 8 + w;

    if (g < NGROUP) {
        const int row0 = g * 16;
        _Float16* s_Aw = &s_A[w][0];

        for (int m = 0; m < 16; m += 4) {
            int e[4], en[4], s[4];
            float a[4][8];
            uint4 v[4];
            #pragma unroll
            for (int i = 0; i < 4; i++) {
                int row = row0 + m + i;
                e[i] = rowPtr[row] + gph;
                en[i] = rowPtr[row + 1];
                #pragma unroll
                for (int j = 0; j < 8; j++) a[i][j] = 0.0f;
            }
            if (gph == 0) {   // self terms
                #pragma unroll
                for (int i = 0; i < 4; i++) {
                    uint4 sv = y4[(size_t)(row0 + m + i) * 8 + cc];
                    float f[8]; unpack8(sv, f);
                    #pragma unroll
                    for (int j = 0; j < 8; j++) a[i][j] = eps1 * f[j];
                }
            }
            #pragma unroll
            for (int i = 0; i < 4; i++) s[i] = (e[i] < en[i]) ? csr_src[e[i]] : -1;
            #pragma unroll
            for (int i = 0; i < 4; i++) if (s[i] >= 0) v[i] = y4[(size_t)s[i] * 8 + cc];

            int mx = max(max(s[0], s[1]), max(s[2], s[3]));
            while (mx >= 0) {
                int n[4]; uint4 p[4];
                #pragma unroll
                for (int i = 0; i < 4; i++) {
                    n[i] = -1;
                    if (s[i] >= 0) { e[i] += 8; n[i] = (e[i] < en[i]) ? csr_src[e[i]] : -1; }
                }
                #pragma unroll
                for (int i = 0; i < 4; i++) if (n[i] >= 0) p[i] = y4[(size_t)n[i] * 8 + cc];
                #pragma unroll
                for (int i = 0; i < 4; i++) {
                    if (s[i] >= 0) {
                        float f[8]; unpack8(v[i], f);
                        #pragma unroll
                        for (int j = 0; j < 8; j++) a[i][j] += f[j];
                    }
                    s[i] = n[i]; v[i] = p[i];
                }
                mx = max(max(s[0], s[1]), max(s[2], s[3]));
            }

            // reduce across the 8 edge slots
            #pragma unroll
            for (int off = 8; off < 64; off <<= 1)
                #pragma unroll
                for (int i = 0; i < 4; i++)
                    #pragma unroll
                    for (int j = 0; j < 8; j++)
                        a[i][j] += __shfl_xor(a[i][j], off, 64);

            if (gph == 0) {   // lanes 0..7; cc==lane holds k=8cc..8cc+7
                #pragma unroll
                for (int i = 0; i < 4; i++) {
                    half8 hv;
                    #pragma unroll
                    for (int j = 0; j < 8; j++)
                        hv[j] = (_Float16)fmaxf(a[i][j] + bav[j], 0.0f);
                    int slot = (cc >> 2) * 64 + (cc & 3) * 16 + (m + i);
                    *(half8*)(s_Aw + (size_t)aswz(slot) * 8) = hv;
                }
            }
        }

        // GEMM2: (16 x 64) @ (64 x 64) via MFMA
        half8 af2[2];
        #pragma unroll
        for (int kc = 0; kc < 2; kc++)
            af2[kc] = *(const half8*)(s_Aw + (size_t)aswz(kc * 64 + lane) * 8);
        floatx4 acc2[4] = {};
        #pragma unroll
        for (int nt = 0; nt < 4; nt++)
            #pragma unroll
            for (int kc = 0; kc < 2; kc++) {
                half8 bf = *(const half8*)(s_B2 + ((size_t)(kc * 4 + nt) * 64 + lane) * 8);
                acc2[nt] = __builtin_amdgcn_mfma_f32_16x16x32_f16(af2[kc], bf, acc2[nt], 0, 0, 0);
            }

        // epilogue: bias + ReLU + BN partials, transpose via LDS, coalesced stores
        #pragma unroll
        for (int nt = 0; nt < 4; nt++)
            #pragma unroll
            for (int r = 0; r < 4; r++) {
                float val = fmaxf(acc2[nt][r] + bbv[nt], 0.0f);
                bn_s[nt] += val;
                bn_q[nt] += val * val;
                s_Aw[(q * 4 + r) * 64 + nt * 16 + mm] = (_Float16)val;
            }
        half8 t0 = *(const half8*)(s_Aw + lane * 8);
        half8 t1 = *(const half8*)(s_Aw + 512 + lane * 8);
        half8* dst = (half8*)((_Float16*)h_out + (size_t)row0 * 64);
        dst[lane] = t0;
        dst[64 + lane] = t1;
    }

    // BN stat reduction (all threads reach barriers)
    #pragma unroll
    for (int nt = 0; nt < 4; nt++) {
        bn_s[nt] += __shfl_xor(bn_s[nt], 16, 64);
        bn_s[nt] += __shfl_xor(bn_s[nt], 32, 64);
        bn_q[nt] += __shfl_xor(bn_q[nt], 16, 64);
        bn_q[nt] += __shfl_xor(bn_q[nt], 32, 64);
    }
    __syncthreads();
    if (lane < 16) {
        #pragma unroll
        for (int nt = 0; nt < 4; nt++) s_red[w][nt * 16 + lane] = bn_s[nt];
    }
    __syncthreads();
    if (w == 0) {
        float s = 0;
        #pragma unroll
        for (int j = 0; j < 8; j++) s += s_red[j][lane];
        atomicAdd(&stats_out[lane], s);
    }
    __syncthreads();
    if (lane < 16) {
        #pragma unroll
        for (int nt = 0; nt < 4; nt++) s_red[w][nt * 16 + lane] = bn_q[nt];
    }
    __syncthreads();
    if (w == 0) {
        float s = 0;
        #pragma unroll
        for (int j = 0; j < 8; j++) s += s_red[j][lane];
        atomicAdd(&stats_out[64 + lane], s);
    }
}

// ---------------- final: BN+ReLU of layer 3 (fp16 h), then (N,64)@(64,10)+b ----------------
__global__ __launch_bounds__(256) void final_linear_kernel(
    const ushort* __restrict__ h, const float* __restrict__ stats,
    const float* __restrict__ g, const float* __restrict__ be,
    const float* __restrict__ w, const float* __restrict__ b,
    float* __restrict__ out)
{
    __shared__ float s_w[640];
    __shared__ float s_b[10];
    __shared__ float s_scale[64];
    __shared__ float s_shift[64];
    for (int i = threadIdx.x; i < 640; i += 256) s_w[i] = w[i];
    if (threadIdx.x < 10) s_b[threadIdx.x] = b[threadIdx.x];
    if (threadIdx.x < 64) {
        int c = threadIdx.x;
        float mean = stats[c] * (1.0f / NN);
        float var  = stats[64 + c] * (1.0f / NN) - mean * mean;
        float rstd = rsqrtf(var + BN_EPS);
        float s    = rstd * g[c];
        s_scale[c] = s;
        s_shift[c] = be[c] - mean * s;
    }
    __syncthreads();
    int row = blockIdx.x * 256 + threadIdx.x;
    if (row >= NN) return;
    float acc[10];
    #pragma unroll
    for (int c = 0; c < 10; c++) acc[c] = s_b[c];
    const uint4* hr = (const uint4*)(h + (size_t)row * 64);
    #pragma unroll
    for (int ch = 0; ch < 8; ch++) {
        uint4 v = hr[ch];
        float f[8]; unpack8(v, f);
        #pragma unroll
        for (int j = 0; j < 8; j++) {
            int k = ch * 8 + j;
            float val = fmaxf(fmaf(f[j], s_scale[k], s_shift[k]), 0.0f);
            #pragma unroll
            for (int c = 0; c < 10; c++) acc[c] = fmaf(val, s_w[k * 10 + c], acc[c]);
        }
    }
    #pragma unroll
    for (int c = 0; c < 10; c++) out[row * 10 + c] = acc[c];
}

extern "C" void kernel_launch(void* const* d_in, const int* in_sizes, int n_in,
                              void* d_out, int out_size, void* d_ws, size_t ws_size,
                              hipStream_t stream)
{
    const float* x  = (const float*)d_in[0];
    const int*   ei = (const int*)d_in[1];
    const int E = in_sizes[1] / 2;

    const float* eps[3]; const float* wa[3]; const float* ba[3];
    const float* wb[3];  const float* bb[3]; const float* g[3]; const float* be[3];
    for (int i = 0; i < 3; i++) {
        int base = 2 + 7 * i;
        eps[i] = (const float*)d_in[base + 0];
        wa[i]  = (const float*)d_in[base + 1];
        ba[i]  = (const float*)d_in[base + 2];
        wb[i]  = (const float*)d_in[base + 3];
        bb[i]  = (const float*)d_in[base + 4];
        g[i]   = (const float*)d_in[base + 5];
        be[i]  = (const float*)d_in[base + 6];
    }
    const float* lin_w = (const float*)d_in[23];
    const float* lin_b = (const float*)d_in[24];
    float* out = (float*)d_out;

    // workspace layout
    const int NB = (NN + 255) / 256;
    char*  base   = (char*)d_ws;
    int*   deg    = (int*)base;               // NN
    int*   rowPtr = deg + NN;                 // NN+1
    int*   cursor = rowPtr + NN + 1;          // NN
    int*   bsum   = cursor + NN;              // 256
    int*   csrsrc = bsum + 256;               // E
    size_t ioff   = (char*)(csrsrc + E) - base;
    ushort* yb    = (ushort*)(base + ((ioff + 15) & ~(size_t)15));  // NN*64
    ushort* hA    = yb + (size_t)NN * 64;     // NN*64
    ushort* hB    = hA + (size_t)NN * 64;     // NN*64
    float* stats  = (float*)(hB + (size_t)NN * 64);  // 3*128

    // ---- CSR build ----
    hipMemsetAsync(deg, 0, NN * sizeof(int), stream);
    hipMemsetAsync(stats, 0, 3 * 128 * sizeof(float), stream);
    hist_kernel<<<(E + 255) / 256, 256, 0, stream>>>(ei, deg, E);
    bsum_kernel<<<NB, 256, 0, stream>>>(deg, bsum);
    bscan_kernel<<<1, 256, 0, stream>>>(bsum, rowPtr, NB, E);
    scan_apply_kernel<<<NB, 256, 0, stream>>>(deg, bsum, rowPtr, cursor);
    fill_csr_kernel<<<(E + 255) / 256, 256, 0, stream>>>(ei, cursor, csrsrc, E);

    const int PB = (NGROUP + 3) / 4;   // 782 proj blocks
    const int GB = (NGROUP + 7) / 8;   // 391 gather blocks

    // ---- layer 1: proj x (fp32,128) -> y; gather ----
    proj_kernel<128, false><<<PB, 256, 0, stream>>>(
        x, nullptr, nullptr, nullptr, wa[0], yb);
    gin_gather_kernel<<<GB, 512, 0, stream>>>(
        yb, rowPtr, csrsrc, eps[0], ba[0], wb[0], bb[0], hA, stats);
    // ---- layer 2: proj BNReLU(hA) -> y; gather ----
    proj_kernel<64, true><<<PB, 256, 0, stream>>>(
        hA, stats, g[0], be[0], wa[1], yb);
    gin_gather_kernel<<<GB, 512, 0, stream>>>(
        yb, rowPtr, csrsrc, eps[1], ba[1], wb[1], bb[1], hB, stats + 128);
    // ---- layer 3: proj BNReLU(hB) -> y; gather ----
    proj_kernel<64, true><<<PB, 256, 0, stream>>>(
        hB, stats + 128, g[1], be[1], wa[2], yb);
    gin_gather_kernel<<<GB, 512, 0, stream>>>(
        yb, rowPtr, csrsrc, eps[2], ba[2], wb[2], bb[2], hA, stats + 256);
    // ---- final linear with BN3+ReLU fused ----
    final_linear_kernel<<<(NN + 255) / 256, 256, 0, stream>>>(
        hA, stats + 256, g[2], be[2], lin_w, lin_b, out);
}